// Round 9
// baseline (504.836 us; speedup 1.0000x reference)
//
#include <hip/hip_runtime.h>
#include <hip/hip_bf16.h>
#include <math.h>

typedef unsigned short u16;
typedef __attribute__((ext_vector_type(8))) short short8;
typedef __attribute__((ext_vector_type(4))) float floatx4;

__device__ __forceinline__ float lk(float v){ return v >= 0.f ? v : 0.01f*v; }
__device__ __forceinline__ u16 f2b(float f){
    __hip_bfloat16 h = __float2bfloat16(f);
    return *reinterpret_cast<u16*>(&h);
}

// ---------------------------------------------------------------------------
// x transpose + bf16 cast + reflect pad: x[128,16,12288] f32 ->
// xT[b][r][16ic] bf16, r in [0,12296), row r holds x[:, reflect(r-3)].
// Memory-bound: coalesced f32 reads per ic, 32B-contiguous row writes.
// ---------------------------------------------------------------------------
__global__ __launch_bounds__(256) void k_xpose(const float* __restrict__ x,
        u16* __restrict__ xT)
{
    int b = blockIdx.x / 49, chunk = blockIdx.x % 49;
    int r = chunk*256 + threadIdx.x;
    if (r >= 12296) return;
    int t = r - 3;
    t = t < 0 ? -t : (t >= 12288 ? 2*12288-2-t : t);
    const float* xb = x + (size_t)b*16*12288 + t;
    u16 v[16];
    #pragma unroll
    for (int ic=0;ic<16;ic++) v[ic] = f2b(xb[(size_t)ic*12288]);
    short8 p0, p1;
    #pragma unroll
    for (int j=0;j<8;j++){ p0[j] = (short)v[j]; p1[j] = (short)v[8+j]; }
    u16* op = xT + ((size_t)b*12296 + r)*16;
    *reinterpret_cast<short8*>(op)     = p0;
    *reinterpret_cast<short8*>(op + 8) = p1;
}

// ---------------------------------------------------------------------------
// Hypernet conv1 (MFMA bf16, NO LDS): xT bf16 -> h1 bf16 [128,32,3072].
// B-fragments (8 contig ic at one position) = one 16B global dwordx4 each.
// No staging, no barrier, no f2b in hot loop. Fragments bit-identical to the
// old LDS path -> same numerics.
// Block = (b, tile of 512 pos); 4 waves = (ohalf x thalf).
// ---------------------------------------------------------------------------
__global__ __launch_bounds__(256) void k_hconv1(const u16* __restrict__ xT,
        const float* __restrict__ w, const float* __restrict__ bias,
        u16* __restrict__ h1)
{
    int b = blockIdx.x / 24, tile = blockIdx.x % 24;
    int g0 = tile*512;
    int tid = threadIdx.x;
    int wv = tid >> 6, lane = tid & 63;
    int m = lane & 15, kq = lane >> 4;
    int ohalf = wv & 1, thalf = wv >> 1;
    int o = ohalf*16 + m;
    short8 wfr[4];
    #pragma unroll
    for (int s=0;s<4;s++){
        int tap = 2*s + (kq>>1);
        #pragma unroll
        for (int j=0;j<8;j++){
            int ic = (kq&1)*8 + j;
            wfr[s][j] = (tap < 7) ? (short)f2b(w[(o*16+ic)*7 + tap]) : (short)0;
        }
    }
    // lane's fragment row base: position = g0 + thalf*256 + sub*16 + m + tap
    const u16* xrow = xT + ((size_t)b*12296 + g0 + thalf*256 + m)*16 + (kq&1)*8;
    floatx4 acc[16];
    #pragma unroll
    for (int i=0;i<16;i++) acc[i] = (floatx4){0.f,0.f,0.f,0.f};
    #pragma unroll
    for (int sub=0; sub<16; sub++){
        #pragma unroll
        for (int s=0;s<4;s++){
            int tap = 2*s + (kq>>1);
            short8 xfr = *reinterpret_cast<const short8*>(xrow + (size_t)(sub*16 + tap)*16);
            acc[sub] = __builtin_amdgcn_mfma_f32_16x16x32_bf16(xfr, wfr[s], acc[sub], 0,0,0);
        }
    }
    float bv = bias[o];
    size_t rowbase = (size_t)(b*32 + o)*3072 + tile*128 + thalf*64 + kq;
    #pragma unroll
    for (int sub=0; sub<16; sub++){
        float sum = lk(acc[sub][0]+bv) + lk(acc[sub][1]+bv)
                  + lk(acc[sub][2]+bv) + lk(acc[sub][3]+bv);
        h1[rowbase + sub*4] = f2b(sum*0.25f);
    }
}

// ---------------------------------------------------------------------------
// Hypernet conv2 (MFMA bf16, positions-on-M): h1 bf16 -> h2 f32. (unchanged)
// ---------------------------------------------------------------------------
__global__ __launch_bounds__(256,1) void k_hconv2(const u16* __restrict__ h1,
        const float* __restrict__ w, const float* __restrict__ bias,
        float* __restrict__ h2)
{
    __shared__ __align__(16) u16 xs[390*40];
    int b = blockIdx.x >> 3, tile = blockIdx.x & 7;
    int g0 = tile*384;
    int tid = threadIdx.x;
    for (int row = tid; row < 390; row += 256){
        int t = g0 + row - 3;
        t = t < 0 ? -t : (t >= 3072 ? 2*3072-2-t : t);
        u16 v[32];
        #pragma unroll
        for (int ic=0;ic<32;ic++) v[ic] = h1[(size_t)(b*32+ic)*3072 + t];
        #pragma unroll
        for (int q=0;q<4;q++){
            short8 p;
            #pragma unroll
            for (int j=0;j<8;j++) p[j] = (short)v[q*8+j];
            *reinterpret_cast<short8*>(&xs[row*40 + q*8]) = p;
        }
    }
    __syncthreads();
    int wv = tid >> 6, lane = tid & 63;
    int m = lane & 15, kq = lane >> 4;
    int o = wv*16 + m;
    short8 wfr[7];
    #pragma unroll
    for (int s=0;s<7;s++){
        #pragma unroll
        for (int j=0;j<8;j++)
            wfr[s][j] = (short)f2b(w[(size_t)(o*32 + kq*8 + j)*7 + s]);
    }
    floatx4 acc[24];
    #pragma unroll
    for (int i=0;i<24;i++) acc[i] = (floatx4){0.f,0.f,0.f,0.f};
    for (int sub=0; sub<24; sub++){
        int tb = sub*16;
        #pragma unroll
        for (int s=0;s<7;s++){
            short8 xfr = *reinterpret_cast<const short8*>(
                            &xs[(tb + m + s)*40 + kq*8]);
            acc[sub] = __builtin_amdgcn_mfma_f32_16x16x32_bf16(xfr, wfr[s], acc[sub], 0,0,0);
        }
    }
    float bv = bias[o];
    size_t rowbase = (size_t)(b*64 + o)*768 + tile*96 + kq;
    #pragma unroll
    for (int sub=0; sub<24; sub++){
        float sum = lk(acc[sub][0]+bv) + lk(acc[sub][1]+bv)
                  + lk(acc[sub][2]+bv) + lk(acc[sub][3]+bv);
        h2[rowbase + sub*4] = sum*0.25f;
    }
}

// ---------------------------------------------------------------------------
// Hypernet conv3 FUSED: h2 f32 -> latent[128,6144]. (unchanged)
// ---------------------------------------------------------------------------
__global__ __launch_bounds__(256) void k_hconv3(const float* __restrict__ h2,
        const float* __restrict__ w, const float* __restrict__ bias,
        float* __restrict__ latent)
{
    __shared__ float xs[64*200];
    int b = blockIdx.x >> 2, tile = blockIdx.x & 3;
    int g0 = tile*192;
    int tid = threadIdx.x;
    const float* hb = h2 + (size_t)b*64*768;
    for (int idx = tid; idx < 64*198; idx += 256){
        int ic = idx / 198, jj = idx - ic*198;
        int t = g0 + jj - 3;
        t = t < 0 ? -t : (t >= 768 ? 2*768-2-t : t);
        xs[ic*200 + jj] = hb[(size_t)ic*768 + t];
    }
    __syncthreads();
    int c = tid >> 5, run = tid & 31;
    int p0 = run*6;
    float acc[6];
    #pragma unroll
    for (int l=0;l<6;l++) acc[l] = 0.f;
    for (int ic=0; ic<64; ic++){
        const float* wp = w + (c*64+ic)*7;
        float wr[7];
        #pragma unroll
        for (int s=0;s<7;s++) wr[s] = wp[s];
        const float* xr = xs + ic*200 + p0;
        float xw[12];
        #pragma unroll
        for (int j=0;j<12;j++) xw[j] = xr[j];
        #pragma unroll
        for (int s=0;s<7;s++)
            #pragma unroll
            for (int l=0;l<6;l++) acc[l] += wr[s]*xw[l+s];
    }
    float bv = bias[c];
    float* op = latent + (size_t)b*6144 + c*768 + g0 + p0;
    #pragma unroll
    for (int l=0;l<6;l++) op[l] = tanhf(acc[l] + bv);
}

// ---------------------------------------------------------------------------
// t1 = leaky(latent @ hl1^T).  (unchanged)
// ---------------------------------------------------------------------------
__global__ __launch_bounds__(256) void k_lin1(const float* __restrict__ latent,
        const float* __restrict__ hl1, float* __restrict__ t1)
{
    __shared__ float ls[6144];
    int b = blockIdx.x / 6, ntile = blockIdx.x % 6;
    int tid = threadIdx.x;
    const float4* lp = reinterpret_cast<const float4*>(latent + (size_t)b*6144);
    float4* lsv = reinterpret_cast<float4*>(ls);
    for (int i = tid; i < 1536; i += 256) lsv[i] = lp[i];
    __syncthreads();
    int wv = tid >> 6, lane = tid & 63;
    #pragma unroll
    for (int nn=0; nn<4; nn++){
        int n = ntile*16 + wv*4 + nn;
        const float4* wp = reinterpret_cast<const float4*>(hl1 + (size_t)n*6144);
        float s = 0.f;
        #pragma unroll
        for (int j=0;j<24;j++){
            float4 q = wp[lane + 64*j];
            float4 l4 = lsv[lane + 64*j];
            s += l4.x*q.x + l4.y*q.y + l4.z*q.z + l4.w*q.w;
        }
        #pragma unroll
        for (int off=32; off; off>>=1) s += __shfl_down(s, off);
        if (lane==0) t1[b*96+n] = lk(s);
    }
}

// ---------------------------------------------------------------------------
// logits = t1 @ hl2^T; top-5; n0 = #(idx<6)   (unchanged)
// ---------------------------------------------------------------------------
__global__ __launch_bounds__(128) void k_topk(const float* __restrict__ t1,
        const float* __restrict__ hl2, int* __restrict__ idxb, float* __restrict__ n0f)
{
    __shared__ float lg[96];
    int b = blockIdx.x, n = threadIdx.x;
    if (n < 96){
        float s = 0.f;
        const float* tp = t1 + b*96;
        const float* wp = hl2 + n*96;
        for (int m=0;m<96;m++) s += tp[m]*wp[m];
        lg[n] = s;
    }
    __syncthreads();
    if (threadIdx.x == 0){
        unsigned long long u0=0ull, u1=0ull;
        float n0 = 0.f;
        for (int k=0;k<5;k++){
            float best = -3.4e38f; int bi = 0;
            for (int m=0;m<96;m++){
                bool used = m<64 ? ((u0>>m)&1ull) : ((u1>>(m-64))&1ull);
                if (!used && lg[m] > best){ best = lg[m]; bi = m; }
            }
            if (bi<64) u0 |= 1ull<<bi; else u1 |= 1ull<<(bi-64);
            idxb[b*5+k] = bi;
            if (bi < 6) n0 += 1.f;
        }
        n0f[b] = n0;
    }
}

// ---------------------------------------------------------------------------
// Grouped idx conv ks=15 + bias + leaky + maxpool4 -> zp bf16 (unchanged)
// ---------------------------------------------------------------------------
__global__ __launch_bounds__(256) void k_gconv(const float* __restrict__ x,
        const int* __restrict__ idxb, const float* __restrict__ n0f,
        const float* __restrict__ gw, const float* __restrict__ gb0,
        u16* __restrict__ zp)
{
    __shared__ float xs[5][522];
    int b = blockIdx.x >> 2, qc = blockIdx.x & 3;
    int tid = threadIdx.x;
    int l0 = qc*508;
    for (int j=tid; j<5*522; j+=256){
        int k = j/522, u = j - k*522;
        int n = idxb[b*5+k];
        xs[k][u] = x[(size_t)b*196608 + n*2048 + l0 + u];
    }
    __syncthreads();
    int o = tid >> 2, qs = tid & 3;
    float wreg[5][15];
    #pragma unroll
    for (int k=0;k<5;k++){
        int n = idxb[b*5+k]; int gi = n/6;
        const float* wp = gw + gi*960 + o*15;
        #pragma unroll
        for (int s=0;s<15;s++) wreg[k][s] = wp[s];
    }
    float bv = n0f[b]*gb0[o];
    for (int q=qs; q<127; q+=4){
        int lb = 4*q;
        float s0=bv, s1=bv, s2=bv, s3=bv;
        #pragma unroll
        for (int k=0;k<5;k++){
            float xw[18];
            #pragma unroll
            for (int j=0;j<18;j++) xw[j] = xs[k][lb+j];
            #pragma unroll
            for (int sp=0;sp<15;sp++){
                s0 += wreg[k][sp]*xw[sp];
                s1 += wreg[k][sp]*xw[sp+1];
                s2 += wreg[k][sp]*xw[sp+2];
                s3 += wreg[k][sp]*xw[sp+3];
            }
        }
        float mx = fmaxf(fmaxf(lk(s0),lk(s1)), fmaxf(lk(s2),lk(s3)));
        zp[((size_t)(b*64+o))*508 + qc*127 + q] = f2b(mx);
    }
}

// ---------------------------------------------------------------------------
// Encoder conv2 (MFMA bf16, positions-on-M): zp bf16 -> p2 f32. (unchanged)
// ---------------------------------------------------------------------------
__global__ __launch_bounds__(256,1) void k_econv2(const u16* __restrict__ zp,
        const float* __restrict__ w, const float* __restrict__ bias,
        float* __restrict__ p2)
{
    __shared__ __align__(16) u16 xs[118*72];
    int b = blockIdx.x / 5, tile = blockIdx.x % 5;
    int tid = threadIdx.x;
    if (tid < 118){
        int t = tile*100 + tid; if (t > 507) t = 507;
        u16 v[64];
        #pragma unroll
        for (int ic=0;ic<64;ic++) v[ic] = zp[(size_t)(b*64+ic)*508 + t];
        #pragma unroll
        for (int q=0;q<8;q++){
            short8 p;
            #pragma unroll
            for (int j=0;j<8;j++) p[j] = (short)v[q*8+j];
            *reinterpret_cast<short8*>(&xs[tid*72 + q*8]) = p;
        }
    }
    __syncthreads();
    int wv = tid >> 6, lane = tid & 63;
    int m = lane & 15, kq = lane >> 4;
    for (int half=0; half<2; half++){
        int ot = wv + 4*half;
        int o = ot*16 + m;
        short8 wfr[14];
        #pragma unroll
        for (int s=0;s<14;s++){
            int ih = s/7, tap = s%7;
            #pragma unroll
            for (int j=0;j<8;j++)
                wfr[s][j] = (short)f2b(w[(size_t)(o*64 + ih*32 + kq*8 + j)*7 + tap]);
        }
        floatx4 acc[7];
        #pragma unroll
        for (int i=0;i<7;i++) acc[i] = (floatx4){0.f,0.f,0.f,0.f};
        #pragma unroll
        for (int sub=0; sub<7; sub++){
            #pragma unroll
            for (int s=0;s<14;s++){
                int ih = s/7, tap = s%7;
                short8 xfr = *reinterpret_cast<const short8*>(
                                &xs[(sub*16 + m + tap)*72 + ih*32 + kq*8]);
                acc[sub] = __builtin_amdgcn_mfma_f32_16x16x32_bf16(xfr, wfr[s], acc[sub], 0,0,0);
            }
        }
        float bv = bias[o];
        #pragma unroll
        for (int sub=0; sub<7; sub++){
            int pidx = sub*4 + kq;
            if (pidx < 25){
                float mx = fmaxf(fmaxf(lk(acc[sub][0]+bv), lk(acc[sub][1]+bv)),
                                 fmaxf(lk(acc[sub][2]+bv), lk(acc[sub][3]+bv)));
                p2[(size_t)(b*128 + o)*125 + tile*25 + pidx] = mx;
            }
        }
    }
}

// ---------------------------------------------------------------------------
// Sliding column sums (unchanged)
// ---------------------------------------------------------------------------
__global__ __launch_bounds__(256) void k_colsum(const float* __restrict__ p2,
        float* __restrict__ ssum)
{
    int g = blockIdx.x*256 + threadIdx.x;
    int ic = g & 127, b = g >> 7;
    const float* pp = p2 + ((size_t)(b*128+ic))*125;
    float c = 0.f;
    for (int t=0;t<119;t++) c += pp[t];
    float* op = ssum + (size_t)(b*128+ic)*7;
    op[0] = c;
    #pragma unroll
    for (int s=0;s<6;s++){ c = c - pp[s] + pp[s+119]; op[s+1] = c; }
}

__global__ __launch_bounds__(128) void k_feat(const float* __restrict__ ssum,
        const float* __restrict__ w, const float* __restrict__ bias,
        float* __restrict__ feat)
{
    __shared__ float ss[896];
    int b = blockIdx.x, o = threadIdx.x;
    for (int j=threadIdx.x; j<896; j+=128) ss[j] = ssum[(size_t)b*896 + j];
    __syncthreads();
    const float* wp = w + o*896;
    float s = 0.f;
    for (int j=0;j<896;j++) s += wp[j]*ss[j];
    feat[b*128+o] = s*(1.f/119.f) + bias[o];
}

__global__ __launch_bounds__(64) void k_cls(const float* __restrict__ feat,
        const float* __restrict__ cw, const float* __restrict__ cb,
        float* __restrict__ out)
{
    __shared__ float lg[5];
    int b = blockIdx.x;
    if (threadIdx.x < 5){
        const float* fp = feat + b*128;
        const float* wp = cw + threadIdx.x*128;
        float s = 0.f;
        for (int o=0;o<128;o++) s += fp[o]*wp[o];
        lg[threadIdx.x] = s + cb[threadIdx.x];
    }
    __syncthreads();
    if (threadIdx.x == 0){
        float mx = -3.4e38f;
        for (int c=0;c<5;c++) mx = fmaxf(mx, lg[c]);
        float se = 0.f;
        for (int c=0;c<5;c++) se += expf(lg[c]-mx);
        float lse = mx + logf(se);
        for (int c=0;c<5;c++) out[b*5+c] = lg[c]-lse;
    }
}

extern "C" void kernel_launch(void* const* d_in, const int* in_sizes, int n_in,
                              void* d_out, int out_size, void* d_ws, size_t ws_size,
                              hipStream_t stream)
{
    const float* x   = (const float*)d_in[0];
    const float* hw1 = (const float*)d_in[2];
    const float* hb1 = (const float*)d_in[3];
    const float* hw2 = (const float*)d_in[4];
    const float* hb2 = (const float*)d_in[5];
    const float* hw3 = (const float*)d_in[6];
    const float* hb3 = (const float*)d_in[7];
    const float* hl1 = (const float*)d_in[8];
    const float* hl2 = (const float*)d_in[9];
    const float* gw  = (const float*)d_in[10];
    const float* gb0 = (const float*)d_in[11];
    const float* ew2 = (const float*)d_in[12];
    const float* eb2 = (const float*)d_in[13];
    const float* ew3 = (const float*)d_in[14];
    const float* eb3 = (const float*)d_in[15];
    const float* cw  = (const float*)d_in[16];
    const float* cb  = (const float*)d_in[17];
    float* out = (float*)d_out;

    // workspace (f32 offsets), peak ~75.6 MB < 91.2 MB proven:
    //   xT  bf16 @ 0          : 128*12296*16 u16 = 12,591,104 f  [dead after hconv1]
    //   h1  bf16 @ 12,600,000 : 6,291,456 f  -> ends 18,891,456  [dead after hconv2]
    //   h2       @ 0 (xT dead): 6,291,456 f
    //   latent   @ 6,300,000  : 786,432
    //   tail: t1 @7.1M, idxb @7.12M, n0f @7.125M, zp @7.13M (2.08M),
    //         p2 @9.3M (2.05M), ssum @11.4M, feat @11.6M
    float* f       = (float*)d_ws;
    u16*   xT      = (u16*)f;
    u16*   h1b     = (u16*)(f + 12600000);
    float* h2      = f;
    float* latent  = f + 6300000;
    float* t1      = f + 7100000;
    int*   idxb    = (int*)(f + 7120000);
    float* n0f     = f + 7125000;
    u16*   zpb     = (u16*)(f + 7130000);
    float* p2      = f + 9300000;
    float* ssum    = f + 11400000;
    float* feat    = f + 11600000;

    k_xpose<<<6272, 256, 0, stream>>>(x, xT);
    k_hconv1<<<3072, 256, 0, stream>>>(xT, hw1, hb1, h1b);
    k_hconv2<<<1024, 256, 0, stream>>>(h1b, hw2, hb2, h2);
    k_hconv3<<<512, 256, 0, stream>>>(h2, hw3, hb3, latent);
    k_lin1<<<768, 256, 0, stream>>>(latent, hl1, t1);
    k_topk<<<128, 128, 0, stream>>>(t1, hl2, idxb, n0f);
    k_gconv<<<512, 256, 0, stream>>>(x, idxb, n0f, gw, gb0, zpb);
    k_econv2<<<640, 256, 0, stream>>>(zpb, ew2, eb2, p2);
    k_colsum<<<64, 256, 0, stream>>>(p2, ssum);
    k_feat<<<128, 128, 0, stream>>>(ssum, ew3, eb3, feat);
    k_cls<<<128, 64, 0, stream>>>(feat, cw, cb, out);
}